// Round 1
// 645.504 us; speedup vs baseline: 1.1843x; 1.1843x over previous
//
#include <hip/hip_runtime.h>
#include <hip/hip_bf16.h>

typedef __attribute__((ext_vector_type(8))) short short8;
typedef __attribute__((ext_vector_type(4))) short short4v;
typedef __attribute__((ext_vector_type(4))) float floatx4;

#define XSTR 136   // bf16 tile stride (272B rows: 16B-aligned, balanced banks for b128 frags)
#define VSTR 56    // bf16 transposed-V / P stride
#define SSTR 132   // fp32 out-stage stride (attn kernels, vec4-friendly)
#define MSTR 129   // fp32 xr stride in fused kernel (odd word stride -> conflict-free)

static __device__ __forceinline__ short f2b(float f) {
    __hip_bfloat16 h = __float2bfloat16(f);
    return *reinterpret_cast<short*>(&h);
}
static __device__ __forceinline__ float b2f(short s) {
    unsigned int u = ((unsigned int)(unsigned short)s) << 16;
    return __uint_as_float(u);
}

// ---------------- weight cast (keeps [n][k] row-major = MFMA B-operand layout) -------
__global__ __launch_bounds__(256) void prep_weights(
    const float* __restrict__ wq0, const float* __restrict__ wkv0,
    const float* __restrict__ wq1, const float* __restrict__ wkv1,
    const float* __restrict__ wq2, const float* __restrict__ wkv2,
    const float* __restrict__ wout0, const float* __restrict__ wout1,
    const float* __restrict__ wout2, const float* __restrict__ w1,
    const float* __restrict__ w2, short* __restrict__ dst)
{
    const int g = blockIdx.x * 256 + threadIdx.x;  // grid exactly covers 229376
    const float* wqs[3]  = { wq0, wq1, wq2 };
    const float* wkvs[3] = { wkv0, wkv1, wkv2 };
    const float* rest[5] = { wout0, wout1, wout2, w1, w2 };
    float val;
    if (g < 147456) {
        const int a = g / 49152, l = g % 49152;
        val = (l < 16384) ? wqs[a][l] : wkvs[a][l - 16384];
    } else {
        const int l = g - 147456;
        val = rest[l >> 14][l & 16383];
    }
    dst[g] = f2b(val);
}

// ---------------- x2 = 2x + px + py + pz, channels-last bf16 -------------------------
__global__ __launch_bounds__(256) void prep_x2(
    const float* __restrict__ x, const float* __restrict__ px,
    const float* __restrict__ py, const float* __restrict__ pz,
    short* __restrict__ x2b)
{
    __shared__ float tile[128 * 49];
    const int s = blockIdx.x, tid = threadIdx.x;
    const int b = s / 2304, rr = s % 2304, xx = rr / 48, yy = rr % 48;
    for (int f = tid; f < 1536; f += 256) {
        const int c = f / 12, z4 = (f % 12) * 4;
        const floatx4 xv = *(const floatx4*)(x + (long)(b * 128 + c) * 110592 + xx * 2304 + yy * 48 + z4);
        const float pxy = px[c * 48 + xx] + py[c * 48 + yy];
        #pragma unroll
        for (int j = 0; j < 4; ++j)
            tile[c * 49 + z4 + j] = 2.0f * xv[j] + pxy + pz[c * 48 + z4 + j];
    }
    __syncthreads();
    const long tb = (long)b * 110592 + xx * 2304 + yy * 48;
    for (int f = tid; f < 1536; f += 256) {
        const int t = f >> 5, c4 = (f & 31) << 2;
        short4v pk;
        #pragma unroll
        for (int j = 0; j < 4; ++j) pk[j] = f2b(tile[(c4 + j) * 49 + t]);
        *(short4v*)(x2b + (tb + t) * 128 + c4) = pk;
    }
}

// ---------------- MFMA axial attention (axes 0/1), 512 threads / 8 waves --------------
// LDS 67840B -> 2 blocks/CU = 16 waves/CU (4 waves/SIMD), was 8 waves/CU at 256thr.
template<int AXIS, int ACC>
__global__ __launch_bounds__(512, 4)
void attn_axis(const short* __restrict__ x2b, const short* __restrict__ wcat,
               const short* __restrict__ woutb, const float* __restrict__ bout,
               short* __restrict__ Ab)
{
    __shared__ __align__(16) char SM[67840];
    short* xs  = (short*)SM;              // [48][XSTR] x2 tile; later O tile
    short* qs  = (short*)(SM + 13056);
    short* ks  = (short*)(SM + 26112);
    short* vs  = (short*)(SM + 39168);    // [128][VSTR] V^T
    short* pb  = (short*)(SM + 53504);    // 8 waves x [16][VSTR] = 14336
    float* stg = (float*)(SM + 13056);    // [48][SSTR] fp32 out stage (aliases qs/ks)

    const int tid  = threadIdx.x;
    const int lane = tid & 63;
    const int wave = tid >> 6;            // 0..7
    const int l15  = lane & 15;
    const int quad = lane >> 4;

    const int s = blockIdx.x;
    const int b = s / 2304, rr = s % 2304, u = rr / 48, v = rr % 48;
    long base; int stride;
    if (AXIS == 0) { base = (long)b * 110592 + u * 48   + v; stride = 2304; }
    else           { base = (long)b * 110592 + u * 2304 + v; stride = 48;   }

    // ---- prefetch A for the RMW (consumed at the very end) ----
    short4v apre[3];
    if (ACC) {
        #pragma unroll
        for (int i = 0; i < 3; ++i) {
            const int f = tid + i * 512;
            const int t = f >> 5, c4 = (f & 31) << 2;
            apre[i] = *(const short4v*)(Ab + (base + (long)t * stride) * 128 + c4);
        }
    }
    // ---- prefetch first QKV weight frag set (no LDS dependency) ----
    short8 bcur[4], bnext[4];
    {
        const short* wp = wcat + (wave * 48 + l15) * 128 + quad * 8;
        #pragma unroll
        for (int k = 0; k < 4; ++k) bcur[k] = *(const short8*)(wp + k * 32);
    }

    // ---- stage x2 tile ----
    for (int f = tid; f < 1536; f += 512) {
        const int t = f >> 5, c4 = (f & 31) << 2;
        *(short4v*)(xs + t * XSTR + c4) =
            *(const short4v*)(x2b + (base + (long)t * stride) * 128 + c4);
    }
    __syncthreads();

    // ---- q/k/v projection: M=48,N=384,K=128; 3 ntiles/wave, pipelined weight frags ----
    short8 af[3][4];
    #pragma unroll
    for (int mt = 0; mt < 3; ++mt)
        #pragma unroll
        for (int k = 0; k < 4; ++k)
            af[mt][k] = *(const short8*)(xs + (mt * 16 + l15) * XSTR + k * 32 + quad * 8);

    for (int nti = 0; nti < 3; ++nti) {
        const int nt = wave * 3 + nti;
        const int n  = nt * 16 + l15;
        if (nti < 2) {
            const short* wp = wcat + ((nt + 1) * 16 + l15) * 128 + quad * 8;
            #pragma unroll
            for (int k = 0; k < 4; ++k) bnext[k] = *(const short8*)(wp + k * 32);
        }
        floatx4 acc[3] = {{0,0,0,0},{0,0,0,0},{0,0,0,0}};
        #pragma unroll
        for (int mt = 0; mt < 3; ++mt)
            #pragma unroll
            for (int k = 0; k < 4; ++k)
                acc[mt] = __builtin_amdgcn_mfma_f32_16x16x32_bf16(af[mt][k], bcur[k], acc[mt], 0, 0, 0);
        #pragma unroll
        for (int mt = 0; mt < 3; ++mt) {
            const int rbase = mt * 16 + quad * 4;
            if (n < 128) {
                #pragma unroll
                for (int g = 0; g < 4; ++g)
                    qs[(rbase + g) * XSTR + n] = f2b(acc[mt][g] * 0.25f);
            } else if (n < 256) {
                #pragma unroll
                for (int g = 0; g < 4; ++g)
                    ks[(rbase + g) * XSTR + (n - 128)] = f2b(acc[mt][g]);
            } else {
                short4v pk;
                #pragma unroll
                for (int g = 0; g < 4; ++g) pk[g] = f2b(acc[mt][g]);
                *(short4v*)(vs + (n - 256) * VSTR + rbase) = pk;
            }
        }
        #pragma unroll
        for (int k = 0; k < 4; ++k) bcur[k] = bnext[k];
    }
    __syncthreads();

    // ---- attention: 24 (head, mtile) tasks over 8 waves; softmax in registers ----
    short* pbw = pb + wave * (16 * VSTR);
    const short8 Z8 = {0,0,0,0,0,0,0,0};
    for (int task = wave; task < 24; task += 8) {
        const int h  = task / 3;
        const int mt = task - h * 3;
        const int hb = h * 16;
        short8 aq = Z8;
        if (quad < 2) aq = *(const short8*)(qs + (mt * 16 + l15) * XSTR + hb + quad * 8);
        floatx4 sc[3];
        #pragma unroll
        for (int nt = 0; nt < 3; ++nt) {
            short8 bk = Z8;
            if (quad < 2) bk = *(const short8*)(ks + (nt * 16 + l15) * XSTR + hb + quad * 8);
            floatx4 z = {0,0,0,0};
            sc[nt] = __builtin_amdgcn_mfma_f32_16x16x32_bf16(aq, bk, z, 0, 0, 0);
        }
        #pragma unroll
        for (int g = 0; g < 4; ++g) {
            float m = fmaxf(fmaxf(sc[0][g], sc[1][g]), sc[2][g]);
            m = fmaxf(m, __shfl_xor(m, 1, 64));
            m = fmaxf(m, __shfl_xor(m, 2, 64));
            m = fmaxf(m, __shfl_xor(m, 4, 64));
            m = fmaxf(m, __shfl_xor(m, 8, 64));
            const float e0 = __expf(sc[0][g] - m);
            const float e1 = __expf(sc[1][g] - m);
            const float e2 = __expf(sc[2][g] - m);
            float ssum = e0 + e1 + e2;
            ssum += __shfl_xor(ssum, 1, 64);
            ssum += __shfl_xor(ssum, 2, 64);
            ssum += __shfl_xor(ssum, 4, 64);
            ssum += __shfl_xor(ssum, 8, 64);
            const float inv = 1.0f / ssum;
            short* prow = pbw + (quad * 4 + g) * VSTR;
            prow[l15]      = f2b(e0 * inv);
            prow[16 + l15] = f2b(e1 * inv);
            prow[32 + l15] = f2b(e2 * inv);
        }
        floatx4 o = {0,0,0,0};
        {
            short8 ap = *(const short8*)(pbw + l15 * VSTR + quad * 8);
            short8 bv = *(const short8*)(vs + (hb + l15) * VSTR + quad * 8);
            o = __builtin_amdgcn_mfma_f32_16x16x32_bf16(ap, bv, o, 0, 0, 0);
            short8 ap1 = Z8, bv1 = Z8;
            if (quad < 2) {
                ap1 = *(const short8*)(pbw + l15 * VSTR + 32 + quad * 8);
                bv1 = *(const short8*)(vs + (hb + l15) * VSTR + 32 + quad * 8);
            }
            o = __builtin_amdgcn_mfma_f32_16x16x32_bf16(ap1, bv1, o, 0, 0, 0);
        }
        #pragma unroll
        for (int g = 0; g < 4; ++g)
            xs[(mt * 16 + quad * 4 + g) * XSTR + hb + l15] = f2b(o[g]);
    }
    __syncthreads();

    // ---- output projection (1 ntile/wave) ----
    #pragma unroll
    for (int mt = 0; mt < 3; ++mt)
        #pragma unroll
        for (int k = 0; k < 4; ++k)
            af[mt][k] = *(const short8*)(xs + (mt * 16 + l15) * XSTR + k * 32 + quad * 8);

    {
        const int n = wave * 16 + l15;
        short8 bf_[4];
        #pragma unroll
        for (int k = 0; k < 4; ++k)
            bf_[k] = *(const short8*)(woutb + n * 128 + k * 32 + quad * 8);
        floatx4 acc[3] = {{0,0,0,0},{0,0,0,0},{0,0,0,0}};
        #pragma unroll
        for (int mt = 0; mt < 3; ++mt)
            #pragma unroll
            for (int k = 0; k < 4; ++k)
                acc[mt] = __builtin_amdgcn_mfma_f32_16x16x32_bf16(af[mt][k], bf_[k], acc[mt], 0, 0, 0);
        const float bo = bout[n];
        #pragma unroll
        for (int mt = 0; mt < 3; ++mt)
            #pragma unroll
            for (int g = 0; g < 4; ++g)
                stg[(mt * 16 + quad * 4 + g) * SSTR + n] = acc[mt][g] + bo;
    }
    __syncthreads();

    // ---- coalesced write / RMW into bf16 A ----
    #pragma unroll
    for (int i = 0; i < 3; ++i) {
        const int f = tid + i * 512;
        const int t = f >> 5, c4 = (f & 31) << 2;
        const long gi = (base + (long)t * stride) * 128 + c4;
        const floatx4 vv = *(const floatx4*)(stg + t * SSTR + c4);
        short4v out4;
        if (ACC) {
            #pragma unroll
            for (int j = 0; j < 4; ++j) out4[j] = f2b(b2f(apre[i][j]) + vv[j]);
        } else {
            #pragma unroll
            for (int j = 0; j < 4; ++j) out4[j] = f2b(vv[j]);
        }
        *(short4v*)(Ab + gi) = out4;
    }
}

// ---------------- fused axis-2 attention + residual + LN1 + MLP + LN2 + out -----------
// 512 threads / 8 waves. x2 residual carried in registers (xpre) so the x2 LDS tile is
// dead after the QKV fragment load -> ob/hbuf alias it. LDS 70272B -> 2 blocks/CU.
static __device__ __forceinline__ void ln_stats129(const float* xr, float* mean_,
                                                   float* rstd_, int tid)
{
    if (tid < 192) {
        const int r = tid >> 2, p = tid & 3;
        const float* row = xr + r * MSTR + p * 32;
        float s1 = 0.f, s2 = 0.f;
        #pragma unroll
        for (int c = 0; c < 32; ++c) { const float xv = row[c]; s1 += xv; s2 += xv * xv; }
        s1 += __shfl_xor(s1, 1, 64); s1 += __shfl_xor(s1, 2, 64);
        s2 += __shfl_xor(s2, 1, 64); s2 += __shfl_xor(s2, 2, 64);
        if (p == 0) {
            const float m = s1 * (1.f / 128.f);
            mean_[r] = m;
            rstd_[r] = rsqrtf(s2 * (1.f / 128.f) - m * m + 1e-5f);
        }
    }
}

__global__ __launch_bounds__(512, 4)
void attn2_mlp(const short* __restrict__ x2b, const short* __restrict__ Ab,
               const short* __restrict__ wcat, const short* __restrict__ woutb,
               const float* __restrict__ bout,
               const float* __restrict__ ln_g, const float* __restrict__ ln_b,
               const short* __restrict__ w1b, const float* __restrict__ b1,
               const short* __restrict__ w2b, const float* __restrict__ b2,
               float* __restrict__ out)
{
    __shared__ __align__(16) char SM[70272];
    short* xs   = (short*)SM;              // x2 stage (QKV) -> O tile -> hbuf
    short* qs   = (short*)(SM + 13056);
    short* ks   = (short*)(SM + 26112);
    short* vs   = (short*)(SM + 39168);    // 14336
    short* pb   = (short*)(SM + 53504);    // 8 waves x [16][VSTR] = 14336
    short* ob   = xs;                      // O tile aliases x2 stage (x2 kept in regs)
    float* xr   = (float*)(SM + 13056);    // [48][MSTR] fp32 (aliases qs+ks)
    short* lnb  = (short*)(SM + 39168);    // aliases vs
    short* hbuf = xs;                      // aliases ob
    float* gs   = (float*)(SM + 67840);
    float* bs   = (float*)(SM + 68352);
    float* b1s  = (float*)(SM + 68864);
    float* b2s  = (float*)(SM + 69376);
    float* mean_ = (float*)(SM + 69888);
    float* rstd_ = (float*)(SM + 70080);

    const int tid  = threadIdx.x;
    const int lane = tid & 63;
    const int wave = tid >> 6;             // 0..7
    const int l15  = lane & 15;
    const int quad = lane >> 4;

    const int s = blockIdx.x;
    const int b = s / 2304, rr = s % 2304, xx = rr / 48, yy = rr % 48;
    const long tb = (long)b * 110592 + xx * 2304 + yy * 48;

    // ---- prefetch attention-sum A (consumed after out-proj) ----
    short4v apre[3];
    #pragma unroll
    for (int i = 0; i < 3; ++i) {
        const int f = tid + i * 512;
        const int t = f >> 5, c4 = (f & 31) << 2;
        apre[i] = *(const short4v*)(Ab + (tb + t) * 128 + c4);
    }
    // ---- prefetch first QKV weight frag set ----
    short8 bcur[4], bnext[4];
    {
        const short* wp = wcat + (wave * 48 + l15) * 128 + quad * 8;
        #pragma unroll
        for (int k = 0; k < 4; ++k) bcur[k] = *(const short8*)(wp + k * 32);
    }

    if (tid < 128) {
        gs[tid] = ln_g[tid]; bs[tid] = ln_b[tid];
        b1s[tid] = b1[tid];  b2s[tid] = b2[tid];
    }
    // ---- stage x2 tile; keep values in registers for the residual ----
    short4v xpre[3];
    #pragma unroll
    for (int i = 0; i < 3; ++i) {
        const int f = tid + i * 512;
        const int t = f >> 5, c4 = (f & 31) << 2;
        xpre[i] = *(const short4v*)(x2b + (tb + t) * 128 + c4);
        *(short4v*)(xs + t * XSTR + c4) = xpre[i];
    }
    __syncthreads();

    // ---- QKV projection ----
    short8 af[3][4];
    #pragma unroll
    for (int mt = 0; mt < 3; ++mt)
        #pragma unroll
        for (int k = 0; k < 4; ++k)
            af[mt][k] = *(const short8*)(xs + (mt * 16 + l15) * XSTR + k * 32 + quad * 8);

    for (int nti = 0; nti < 3; ++nti) {
        const int nt = wave * 3 + nti;
        const int n  = nt * 16 + l15;
        if (nti < 2) {
            const short* wp = wcat + ((nt + 1) * 16 + l15) * 128 + quad * 8;
            #pragma unroll
            for (int k = 0; k < 4; ++k) bnext[k] = *(const short8*)(wp + k * 32);
        }
        floatx4 acc[3] = {{0,0,0,0},{0,0,0,0},{0,0,0,0}};
        #pragma unroll
        for (int mt = 0; mt < 3; ++mt)
            #pragma unroll
            for (int k = 0; k < 4; ++k)
                acc[mt] = __builtin_amdgcn_mfma_f32_16x16x32_bf16(af[mt][k], bcur[k], acc[mt], 0, 0, 0);
        #pragma unroll
        for (int mt = 0; mt < 3; ++mt) {
            const int rbase = mt * 16 + quad * 4;
            if (n < 128) {
                #pragma unroll
                for (int g = 0; g < 4; ++g)
                    qs[(rbase + g) * XSTR + n] = f2b(acc[mt][g] * 0.25f);
            } else if (n < 256) {
                #pragma unroll
                for (int g = 0; g < 4; ++g)
                    ks[(rbase + g) * XSTR + (n - 128)] = f2b(acc[mt][g]);
            } else {
                short4v pk;
                #pragma unroll
                for (int g = 0; g < 4; ++g) pk[g] = f2b(acc[mt][g]);
                *(short4v*)(vs + (n - 256) * VSTR + rbase) = pk;
            }
        }
        #pragma unroll
        for (int k = 0; k < 4; ++k) bcur[k] = bnext[k];
    }
    __syncthreads();

    // ---- attention tasks (O -> ob) ----
    short* pbw = pb + wave * (16 * VSTR);
    const short8 Z8 = {0,0,0,0,0,0,0,0};
    for (int task = wave; task < 24; task += 8) {
        const int h  = task / 3;
        const int mt = task - h * 3;
        const int hb = h * 16;
        short8 aq = Z8;
        if (quad < 2) aq = *(const short8*)(qs + (mt * 16 + l15) * XSTR + hb + quad * 8);
        floatx4 sc[3];
        #pragma unroll
        for (int nt = 0; nt < 3; ++nt) {
            short8 bk = Z8;
            if (quad < 2) bk = *(const short8*)(ks + (nt * 16 + l15) * XSTR + hb + quad * 8);
            floatx4 z = {0,0,0,0};
            sc[nt] = __builtin_amdgcn_mfma_f32_16x16x32_bf16(aq, bk, z, 0, 0, 0);
        }
        #pragma unroll
        for (int g = 0; g < 4; ++g) {
            float m = fmaxf(fmaxf(sc[0][g], sc[1][g]), sc[2][g]);
            m = fmaxf(m, __shfl_xor(m, 1, 64));
            m = fmaxf(m, __shfl_xor(m, 2, 64));
            m = fmaxf(m, __shfl_xor(m, 4, 64));
            m = fmaxf(m, __shfl_xor(m, 8, 64));
            const float e0 = __expf(sc[0][g] - m);
            const float e1 = __expf(sc[1][g] - m);
            const float e2 = __expf(sc[2][g] - m);
            float ssum = e0 + e1 + e2;
            ssum += __shfl_xor(ssum, 1, 64);
            ssum += __shfl_xor(ssum, 2, 64);
            ssum += __shfl_xor(ssum, 4, 64);
            ssum += __shfl_xor(ssum, 8, 64);
            const float inv = 1.0f / ssum;
            short* prow = pbw + (quad * 4 + g) * VSTR;
            prow[l15]      = f2b(e0 * inv);
            prow[16 + l15] = f2b(e1 * inv);
            prow[32 + l15] = f2b(e2 * inv);
        }
        floatx4 o = {0,0,0,0};
        {
            short8 ap = *(const short8*)(pbw + l15 * VSTR + quad * 8);
            short8 bv = *(const short8*)(vs + (hb + l15) * VSTR + quad * 8);
            o = __builtin_amdgcn_mfma_f32_16x16x32_bf16(ap, bv, o, 0, 0, 0);
            short8 ap1 = Z8, bv1 = Z8;
            if (quad < 2) {
                ap1 = *(const short8*)(pbw + l15 * VSTR + 32 + quad * 8);
                bv1 = *(const short8*)(vs + (hb + l15) * VSTR + 32 + quad * 8);
            }
            o = __builtin_amdgcn_mfma_f32_16x16x32_bf16(ap1, bv1, o, 0, 0, 0);
        }
        #pragma unroll
        for (int g = 0; g < 4; ++g)
            ob[(mt * 16 + quad * 4 + g) * XSTR + hb + l15] = f2b(o[g]);
    }
    __syncthreads();

    // ---- output projection -> xr (fp32, + bias); 1 ntile/wave ----
    #pragma unroll
    for (int mt = 0; mt < 3; ++mt)
        #pragma unroll
        for (int k = 0; k < 4; ++k)
            af[mt][k] = *(const short8*)(ob + (mt * 16 + l15) * XSTR + k * 32 + quad * 8);
    {
        const int n = wave * 16 + l15;
        short8 bf_[4];
        #pragma unroll
        for (int k = 0; k < 4; ++k)
            bf_[k] = *(const short8*)(woutb + n * 128 + k * 32 + quad * 8);
        floatx4 acc[3] = {{0,0,0,0},{0,0,0,0},{0,0,0,0}};
        #pragma unroll
        for (int mt = 0; mt < 3; ++mt)
            #pragma unroll
            for (int k = 0; k < 4; ++k)
                acc[mt] = __builtin_amdgcn_mfma_f32_16x16x32_bf16(af[mt][k], bf_[k], acc[mt], 0, 0, 0);
        const float bo = bout[n];
        #pragma unroll
        for (int mt = 0; mt < 3; ++mt)
            #pragma unroll
            for (int g = 0; g < 4; ++g)
                xr[(mt * 16 + quad * 4 + g) * MSTR + n] = acc[mt][g] + bo;
    }
    __syncthreads();

    // ---- residual: xr += A(prefetched) + x2(registers) ----
    #pragma unroll
    for (int i = 0; i < 3; ++i) {
        const int f = tid + i * 512;
        const int t = f >> 5, c4 = (f & 31) << 2;
        #pragma unroll
        for (int j = 0; j < 4; ++j)
            xr[t * MSTR + c4 + j] += b2f(apre[i][j]) + b2f(xpre[i][j]);
    }
    __syncthreads();

    ln_stats129(xr, mean_, rstd_, tid);
    __syncthreads();
    for (int f = tid; f < 6144; f += 512) {
        const int t = f >> 7, c = f & 127;
        lnb[t * XSTR + c] = f2b((xr[t * MSTR + c] - mean_[t]) * rstd_[t] * gs[c] + bs[c]);
    }
    __syncthreads();

    // ---- MLP GEMM1 + relu ----
    #pragma unroll
    for (int mt = 0; mt < 3; ++mt)
        #pragma unroll
        for (int k = 0; k < 4; ++k)
            af[mt][k] = *(const short8*)(lnb + (mt * 16 + l15) * XSTR + k * 32 + quad * 8);
    {
        const int n = wave * 16 + l15;
        short8 bf_[4];
        #pragma unroll
        for (int k = 0; k < 4; ++k)
            bf_[k] = *(const short8*)(w1b + n * 128 + k * 32 + quad * 8);
        floatx4 acc[3] = {{0,0,0,0},{0,0,0,0},{0,0,0,0}};
        #pragma unroll
        for (int mt = 0; mt < 3; ++mt)
            #pragma unroll
            for (int k = 0; k < 4; ++k)
                acc[mt] = __builtin_amdgcn_mfma_f32_16x16x32_bf16(af[mt][k], bf_[k], acc[mt], 0, 0, 0);
        const float bb = b1s[n];
        #pragma unroll
        for (int mt = 0; mt < 3; ++mt)
            #pragma unroll
            for (int g = 0; g < 4; ++g)
                hbuf[(mt * 16 + quad * 4 + g) * XSTR + n] = f2b(fmaxf(acc[mt][g] + bb, 0.f));
    }
    __syncthreads();

    // ---- MLP GEMM2 + inner residual (fp32-recomputed ln1) ----
    #pragma unroll
    for (int mt = 0; mt < 3; ++mt)
        #pragma unroll
        for (int k = 0; k < 4; ++k)
            af[mt][k] = *(const short8*)(hbuf + (mt * 16 + l15) * XSTR + k * 32 + quad * 8);
    {
        const int n = wave * 16 + l15;
        short8 bf_[4];
        #pragma unroll
        for (int k = 0; k < 4; ++k)
            bf_[k] = *(const short8*)(w2b + n * 128 + k * 32 + quad * 8);
        floatx4 acc[3] = {{0,0,0,0},{0,0,0,0},{0,0,0,0}};
        #pragma unroll
        for (int mt = 0; mt < 3; ++mt)
            #pragma unroll
            for (int k = 0; k < 4; ++k)
                acc[mt] = __builtin_amdgcn_mfma_f32_16x16x32_bf16(af[mt][k], bf_[k], acc[mt], 0, 0, 0);
        const float bb = b2s[n];
        #pragma unroll
        for (int mt = 0; mt < 3; ++mt)
            #pragma unroll
            for (int g = 0; g < 4; ++g) {
                const int t = mt * 16 + quad * 4 + g;
                const float ln1 = (xr[t * MSTR + n] - mean_[t]) * rstd_[t] * gs[n] + bs[n];
                xr[t * MSTR + n] = acc[mt][g] + bb + ln1;
            }
    }
    __syncthreads();
    ln_stats129(xr, mean_, rstd_, tid);
    __syncthreads();

    // ---- channels-first vectorized output ----
    for (int f = tid; f < 1536; f += 512) {
        const int c = f / 12, z4 = (f % 12) * 4;
        floatx4 o4;
        #pragma unroll
        for (int j = 0; j < 4; ++j)
            o4[j] = (xr[(z4 + j) * MSTR + c] - mean_[z4 + j]) * rstd_[z4 + j] * gs[c] + bs[c];
        *(floatx4*)(out + (long)(b * 128 + c) * 110592 + xx * 2304 + yy * 48 + z4) = o4;
    }
}

// -------------------------------------------------------------------------------------
extern "C" void kernel_launch(void* const* d_in, const int* in_sizes, int n_in,
                              void* d_out, int out_size, void* d_ws, size_t ws_size,
                              hipStream_t stream)
{
    const float* x    = (const float*)d_in[0];
    const float* px   = (const float*)d_in[1];
    const float* py   = (const float*)d_in[2];
    const float* pz   = (const float*)d_in[3];
    const float* wq[3]   = { (const float*)d_in[4],  (const float*)d_in[8],  (const float*)d_in[12] };
    const float* wkv[3]  = { (const float*)d_in[5],  (const float*)d_in[9],  (const float*)d_in[13] };
    const float* wout[3] = { (const float*)d_in[6],  (const float*)d_in[10], (const float*)d_in[14] };
    const float* bout[3] = { (const float*)d_in[7],  (const float*)d_in[11], (const float*)d_in[15] };
    const float* ln_g = (const float*)d_in[16];
    const float* ln_b = (const float*)d_in[17];
    const float* w1   = (const float*)d_in[18];
    const float* b1   = (const float*)d_in[19];
    const float* w2   = (const float*)d_in[20];
    const float* b2   = (const float*)d_in[21];

    // ws: A bf16 (56,623,104 B) | weights bf16 (458,752 B) | x2b bf16 (56,623,104 B)
    short* Ab  = (short*)d_ws;
    short* wb  = (short*)((char*)d_ws + 56623104);
    short* x2b = (short*)((char*)d_ws + 57081856);

    prep_weights<<<896, 256, 0, stream>>>(wq[0], wkv[0], wq[1], wkv[1], wq[2], wkv[2],
                                          wout[0], wout[1], wout[2], w1, w2, wb);
    prep_x2<<<4608, 256, 0, stream>>>(x, px, py, pz, x2b);

    attn_axis<0, 0><<<4608, 512, 0, stream>>>(x2b, wb,         wb + 147456, bout[0], Ab);
    attn_axis<1, 1><<<4608, 512, 0, stream>>>(x2b, wb + 49152, wb + 163840, bout[1], Ab);

    attn2_mlp<<<4608, 512, 0, stream>>>(x2b, Ab, wb + 98304, wb + 180224, bout[2],
                                        ln_g, ln_b, wb + 196608, b1, wb + 212992, b2,
                                        (float*)d_out);
}

// Round 3
// 601.594 us; speedup vs baseline: 1.2707x; 1.0730x over previous
//
#include <hip/hip_runtime.h>
#include <hip/hip_bf16.h>

typedef __attribute__((ext_vector_type(8))) short short8;
typedef __attribute__((ext_vector_type(4))) short short4v;
typedef __attribute__((ext_vector_type(4))) float floatx4;

#define XSTR 136   // bf16 tile stride (272B rows: balanced banks for b128 frags)
#define VSTR 48    // bf16 transposed-V / P stride (96B rows: b128/b64 bank-balanced)
#define SSTR 132   // fp32 out-stage stride (attn kernels, vec4-friendly)
#define MSTR 129   // fp32 xr stride in fused kernel (odd word stride -> conflict-free)

static __device__ __forceinline__ short f2b(float f) {
    __hip_bfloat16 h = __float2bfloat16(f);
    return *reinterpret_cast<short*>(&h);
}
static __device__ __forceinline__ float b2f(short s) {
    unsigned int u = ((unsigned int)(unsigned short)s) << 16;
    return __uint_as_float(u);
}

// ---------------- weight cast (keeps [n][k] row-major = MFMA B-operand layout) -------
__global__ __launch_bounds__(256) void prep_weights(
    const float* __restrict__ wq0, const float* __restrict__ wkv0,
    const float* __restrict__ wq1, const float* __restrict__ wkv1,
    const float* __restrict__ wq2, const float* __restrict__ wkv2,
    const float* __restrict__ wout0, const float* __restrict__ wout1,
    const float* __restrict__ wout2, const float* __restrict__ w1,
    const float* __restrict__ w2, short* __restrict__ dst)
{
    const int g = blockIdx.x * 256 + threadIdx.x;  // grid exactly covers 229376
    const float* wqs[3]  = { wq0, wq1, wq2 };
    const float* wkvs[3] = { wkv0, wkv1, wkv2 };
    const float* rest[5] = { wout0, wout1, wout2, w1, w2 };
    float val;
    if (g < 147456) {
        const int a = g / 49152, l = g % 49152;
        val = (l < 16384) ? wqs[a][l] : wkvs[a][l - 16384];
    } else {
        const int l = g - 147456;
        val = rest[l >> 14][l & 16383];
    }
    dst[g] = f2b(val);
}

// ---------------- x2 = 2x + px + py + pz, channels-last bf16 -------------------------
__global__ __launch_bounds__(256) void prep_x2(
    const float* __restrict__ x, const float* __restrict__ px,
    const float* __restrict__ py, const float* __restrict__ pz,
    short* __restrict__ x2b)
{
    __shared__ float tile[128 * 49];
    const int s = blockIdx.x, tid = threadIdx.x;
    const int b = s / 2304, rr = s % 2304, xx = rr / 48, yy = rr % 48;
    for (int f = tid; f < 1536; f += 256) {
        const int c = f / 12, z4 = (f % 12) * 4;
        const floatx4 xv = *(const floatx4*)(x + (long)(b * 128 + c) * 110592 + xx * 2304 + yy * 48 + z4);
        const float pxy = px[c * 48 + xx] + py[c * 48 + yy];
        #pragma unroll
        for (int j = 0; j < 4; ++j)
            tile[c * 49 + z4 + j] = 2.0f * xv[j] + pxy + pz[c * 48 + z4 + j];
    }
    __syncthreads();
    const long tb = (long)b * 110592 + xx * 2304 + yy * 48;
    for (int f = tid; f < 1536; f += 256) {
        const int t = f >> 5, c4 = (f & 31) << 2;
        short4v pk;
        #pragma unroll
        for (int j = 0; j < 4; ++j) pk[j] = f2b(tile[(c4 + j) * 49 + t]);
        *(short4v*)(x2b + (tb + t) * 128 + c4) = pk;
    }
}

// ---------------- MFMA axial attention (axes 0/1), 512 threads / 8 waves --------------
// wave=head: wave w computes QKV n-tiles {w, w+8, w+16} and attends head w entirely.
// QKV -> attention is intra-wave (no barrier); O goes to separate ob buffer.
template<int AXIS, int ACC>
__global__ __launch_bounds__(512, 4)
void attn_axis(const short* __restrict__ x2b, const short* __restrict__ wcat,
               const short* __restrict__ woutb, const float* __restrict__ bout,
               short* __restrict__ Ab)
{
    __shared__ __align__(16) char SM[76800];
    short* xs  = (short*)SM;              // [48][XSTR] x2 tile
    short* qs  = (short*)(SM + 13056);
    short* ks  = (short*)(SM + 26112);
    short* vs  = (short*)(SM + 39168);    // [128][VSTR] V^T, 12288
    short* pb  = (short*)(SM + 51456);    // 8 waves x [16][VSTR] = 12288
    short* ob  = (short*)(SM + 63744);    // [48][XSTR] O tile, 13056
    float* stg = (float*)(SM + 13056);    // [48][SSTR] fp32 out stage (aliases qs/ks)

    const int tid  = threadIdx.x;
    const int lane = tid & 63;
    const int wave = tid >> 6;            // 0..7 == head
    const int l15  = lane & 15;
    const int quad = lane >> 4;

    const int s = blockIdx.x;
    const int b = s / 2304, rr = s % 2304, u = rr / 48, v = rr % 48;
    long base; int stride;
    if (AXIS == 0) { base = (long)b * 110592 + u * 48   + v; stride = 2304; }
    else           { base = (long)b * 110592 + u * 2304 + v; stride = 48;   }

    // ---- prefetch A for the RMW (consumed at the very end) ----
    short4v apre[3];
    if (ACC) {
        #pragma unroll
        for (int i = 0; i < 3; ++i) {
            const int f = tid + i * 512;
            const int t = f >> 5, c4 = (f & 31) << 2;
            apre[i] = *(const short4v*)(Ab + (base + (long)t * stride) * 128 + c4);
        }
    }
    // ---- prefetch Q-tile weights (n-tile = wave) ----
    short8 bcur[4], bnext[4];
    {
        const short* wp = wcat + (wave * 16 + l15) * 128 + quad * 8;
        #pragma unroll
        for (int k = 0; k < 4; ++k) bcur[k] = *(const short8*)(wp + k * 32);
    }

    // ---- stage x2 tile ----
    for (int f = tid; f < 1536; f += 512) {
        const int t = f >> 5, c4 = (f & 31) << 2;
        *(short4v*)(xs + t * XSTR + c4) =
            *(const short4v*)(x2b + (base + (long)t * stride) * 128 + c4);
    }
    __syncthreads();

    // ---- QKV projection: wave w owns head w's q/k/v columns ----
    short8 af[3][4];
    #pragma unroll
    for (int mt = 0; mt < 3; ++mt)
        #pragma unroll
        for (int k = 0; k < 4; ++k)
            af[mt][k] = *(const short8*)(xs + (mt * 16 + l15) * XSTR + k * 32 + quad * 8);

    const int n0 = wave * 16 + l15;       // column within each 128-wide segment
    // Q tile (bcur); prefetch K weights
    {
        const short* wp = wcat + ((wave + 8) * 16 + l15) * 128 + quad * 8;
        #pragma unroll
        for (int k = 0; k < 4; ++k) bnext[k] = *(const short8*)(wp + k * 32);
        floatx4 acc[3] = {{0,0,0,0},{0,0,0,0},{0,0,0,0}};
        #pragma unroll
        for (int mt = 0; mt < 3; ++mt)
            #pragma unroll
            for (int k = 0; k < 4; ++k)
                acc[mt] = __builtin_amdgcn_mfma_f32_16x16x32_bf16(af[mt][k], bcur[k], acc[mt], 0, 0, 0);
        #pragma unroll
        for (int mt = 0; mt < 3; ++mt) {
            const int rbase = mt * 16 + quad * 4;
            #pragma unroll
            for (int g = 0; g < 4; ++g)
                qs[(rbase + g) * XSTR + n0] = f2b(acc[mt][g] * 0.25f);
        }
    }
    // K tile (bnext); prefetch V weights into bcur
    {
        const short* wp = wcat + ((wave + 16) * 16 + l15) * 128 + quad * 8;
        #pragma unroll
        for (int k = 0; k < 4; ++k) bcur[k] = *(const short8*)(wp + k * 32);
        floatx4 acc[3] = {{0,0,0,0},{0,0,0,0},{0,0,0,0}};
        #pragma unroll
        for (int mt = 0; mt < 3; ++mt)
            #pragma unroll
            for (int k = 0; k < 4; ++k)
                acc[mt] = __builtin_amdgcn_mfma_f32_16x16x32_bf16(af[mt][k], bnext[k], acc[mt], 0, 0, 0);
        #pragma unroll
        for (int mt = 0; mt < 3; ++mt) {
            const int rbase = mt * 16 + quad * 4;
            #pragma unroll
            for (int g = 0; g < 4; ++g)
                ks[(rbase + g) * XSTR + n0] = f2b(acc[mt][g]);
        }
    }
    // V tile (bcur), transposed store
    {
        floatx4 acc[3] = {{0,0,0,0},{0,0,0,0},{0,0,0,0}};
        #pragma unroll
        for (int mt = 0; mt < 3; ++mt)
            #pragma unroll
            for (int k = 0; k < 4; ++k)
                acc[mt] = __builtin_amdgcn_mfma_f32_16x16x32_bf16(af[mt][k], bcur[k], acc[mt], 0, 0, 0);
        #pragma unroll
        for (int mt = 0; mt < 3; ++mt) {
            short4v pk;
            #pragma unroll
            for (int g = 0; g < 4; ++g) pk[g] = f2b(acc[mt][g]);
            *(short4v*)(vs + n0 * VSTR + mt * 16 + quad * 4) = pk;
        }
    }

    // ---- attention, head = wave; K/V fragments hoisted across the 3 m-tiles ----
    // (intra-wave LDS RAW on qs/ks/vs/pb: compiler inserts lgkmcnt, no barrier needed)
    short* pbw = pb + wave * (16 * VSTR);
    const short8 Z8 = {0,0,0,0,0,0,0,0};
    const int hb = wave * 16;
    short8 bk[3], bv0, bv1;
    #pragma unroll
    for (int nt = 0; nt < 3; ++nt) {
        bk[nt] = Z8;
        if (quad < 2) bk[nt] = *(const short8*)(ks + (nt * 16 + l15) * XSTR + hb + quad * 8);
    }
    bv0 = *(const short8*)(vs + (hb + l15) * VSTR + quad * 8);
    bv1 = Z8;
    if (quad < 2) bv1 = *(const short8*)(vs + (hb + l15) * VSTR + 32 + quad * 8);

    #pragma unroll
    for (int mt = 0; mt < 3; ++mt) {
        short8 aq = Z8;
        if (quad < 2) aq = *(const short8*)(qs + (mt * 16 + l15) * XSTR + hb + quad * 8);
        floatx4 sc[3];
        #pragma unroll
        for (int nt = 0; nt < 3; ++nt) {
            floatx4 z = {0,0,0,0};
            sc[nt] = __builtin_amdgcn_mfma_f32_16x16x32_bf16(aq, bk[nt], z, 0, 0, 0);
        }
        // softmax without max-shift: scores ~N(0,0.36), |s|<10 guaranteed
        #pragma unroll
        for (int g = 0; g < 4; ++g) {
            const float e0 = __expf(sc[0][g]);
            const float e1 = __expf(sc[1][g]);
            const float e2 = __expf(sc[2][g]);
            float ssum = e0 + e1 + e2;
            ssum += __shfl_xor(ssum, 1, 64);
            ssum += __shfl_xor(ssum, 2, 64);
            ssum += __shfl_xor(ssum, 4, 64);
            ssum += __shfl_xor(ssum, 8, 64);
            const float inv = 1.0f / ssum;
            short* prow = pbw + (quad * 4 + g) * VSTR;
            prow[l15]      = f2b(e0 * inv);
            prow[16 + l15] = f2b(e1 * inv);
            prow[32 + l15] = f2b(e2 * inv);
        }
        floatx4 o = {0,0,0,0};
        {
            short8 ap = *(const short8*)(pbw + l15 * VSTR + quad * 8);
            o = __builtin_amdgcn_mfma_f32_16x16x32_bf16(ap, bv0, o, 0, 0, 0);
            short8 ap1 = Z8;
            if (quad < 2) ap1 = *(const short8*)(pbw + l15 * VSTR + 32 + quad * 8);
            o = __builtin_amdgcn_mfma_f32_16x16x32_bf16(ap1, bv1, o, 0, 0, 0);
        }
        #pragma unroll
        for (int g = 0; g < 4; ++g)
            ob[(mt * 16 + quad * 4 + g) * XSTR + hb + l15] = f2b(o[g]);
    }
    __syncthreads();

    // ---- output projection (1 ntile/wave) ----
    #pragma unroll
    for (int mt = 0; mt < 3; ++mt)
        #pragma unroll
        for (int k = 0; k < 4; ++k)
            af[mt][k] = *(const short8*)(ob + (mt * 16 + l15) * XSTR + k * 32 + quad * 8);
    {
        const int n = wave * 16 + l15;
        short8 bf_[4];
        #pragma unroll
        for (int k = 0; k < 4; ++k)
            bf_[k] = *(const short8*)(woutb + n * 128 + k * 32 + quad * 8);
        floatx4 acc[3] = {{0,0,0,0},{0,0,0,0},{0,0,0,0}};
        #pragma unroll
        for (int mt = 0; mt < 3; ++mt)
            #pragma unroll
            for (int k = 0; k < 4; ++k)
                acc[mt] = __builtin_amdgcn_mfma_f32_16x16x32_bf16(af[mt][k], bf_[k], acc[mt], 0, 0, 0);
        const float bo = bout[n];
        #pragma unroll
        for (int mt = 0; mt < 3; ++mt)
            #pragma unroll
            for (int g = 0; g < 4; ++g)
                stg[(mt * 16 + quad * 4 + g) * SSTR + n] = acc[mt][g] + bo;
    }
    __syncthreads();

    // ---- coalesced write / RMW into bf16 A ----
    #pragma unroll
    for (int i = 0; i < 3; ++i) {
        const int f = tid + i * 512;
        const int t = f >> 5, c4 = (f & 31) << 2;
        const long gi = (base + (long)t * stride) * 128 + c4;
        const floatx4 vv = *(const floatx4*)(stg + t * SSTR + c4);
        short4v out4;
        if (ACC) {
            #pragma unroll
            for (int j = 0; j < 4; ++j) out4[j] = f2b(b2f(apre[i][j]) + vv[j]);
        } else {
            #pragma unroll
            for (int j = 0; j < 4; ++j) out4[j] = f2b(vv[j]);
        }
        *(short4v*)(Ab + gi) = out4;
    }
}

// ---------------- fused axis-2 attention + residual + LN1 + MLP + LN2 + out -----------
// LN2 stats (cross-wave layout): per-lane rotation breaks the 4-way bank conflict.
static __device__ __forceinline__ void ln_stats129(const float* xr, float* mean_,
                                                   float* rstd_, int tid)
{
    if (tid < 192) {
        const int r = tid >> 2, p = tid & 3;
        const float* row = xr + r * MSTR + p * 32;
        float s1 = 0.f, s2 = 0.f;
        #pragma unroll
        for (int c0 = 0; c0 < 32; ++c0) {
            const float xv = row[(c0 + p * 8) & 31];
            s1 += xv; s2 += xv * xv;
        }
        s1 += __shfl_xor(s1, 1, 64); s1 += __shfl_xor(s1, 2, 64);
        s2 += __shfl_xor(s2, 1, 64); s2 += __shfl_xor(s2, 2, 64);
        if (p == 0) {
            const float m = s1 * (1.f / 128.f);
            mean_[r] = m;
            rstd_[r] = rsqrtf(s2 * (1.f / 128.f) - m * m + 1e-5f);
        }
    }
}

__global__ __launch_bounds__(512, 4)
void attn2_mlp(const short* __restrict__ x2b, const short* __restrict__ Ab,
               const short* __restrict__ wcat, const short* __restrict__ woutb,
               const float* __restrict__ bout,
               const float* __restrict__ ln_g, const float* __restrict__ ln_b,
               const short* __restrict__ w1b, const float* __restrict__ b1,
               const short* __restrict__ w2b, const float* __restrict__ b2,
               float* __restrict__ out)
{
    __shared__ __align__(16) char SM[79232];
    short* xs   = (short*)SM;              // [48][XSTR] x2 stage
    short* qs   = (short*)(SM + 13056);
    short* ks   = (short*)(SM + 26112);
    short* vs   = (short*)(SM + 39168);    // 12288
    short* pb   = (short*)(SM + 51456);    // 12288
    short* ob   = (short*)(SM + 63744);    // 13056; later hbuf
    float* xr   = (float*)(SM + 13056);    // [48][MSTR] fp32 (aliases qs+ks, 24768)
    short* lnb  = (short*)(SM + 39168);    // 13056 (aliases vs + head of pb; pb dead)
    short* hbuf = (short*)(SM + 63744);    // aliases ob
    float* gs   = (float*)(SM + 76800);
    float* bs   = (float*)(SM + 77312);
    float* b1s  = (float*)(SM + 77824);
    float* b2s  = (float*)(SM + 78336);
    float* mean_ = (float*)(SM + 78848);
    float* rstd_ = (float*)(SM + 79040);

    const int tid  = threadIdx.x;
    const int lane = tid & 63;
    const int wave = tid >> 6;             // 0..7 == head
    const int l15  = lane & 15;
    const int quad = lane >> 4;

    const int s = blockIdx.x;
    const int b = s / 2304, rr = s % 2304, xx = rr / 48, yy = rr % 48;
    const long tb = (long)b * 110592 + xx * 2304 + yy * 48;

    // ---- prefetch attention-sum A (consumed in residual) ----
    short4v apre[3];
    #pragma unroll
    for (int i = 0; i < 3; ++i) {
        const int f = tid + i * 512;
        const int t = f >> 5, c4 = (f & 31) << 2;
        apre[i] = *(const short4v*)(Ab + (tb + t) * 128 + c4);
    }
    // ---- prefetch Q-tile weights (n-tile = wave) ----
    short8 bcur[4], bnext[4];
    {
        const short* wp = wcat + (wave * 16 + l15) * 128 + quad * 8;
        #pragma unroll
        for (int k = 0; k < 4; ++k) bcur[k] = *(const short8*)(wp + k * 32);
    }

    if (tid < 128) {
        gs[tid] = ln_g[tid]; bs[tid] = ln_b[tid];
        b1s[tid] = b1[tid];  b2s[tid] = b2[tid];
    }
    // ---- stage x2 tile; keep values in registers for the residual ----
    short4v xpre[3];
    #pragma unroll
    for (int i = 0; i < 3; ++i) {
        const int f = tid + i * 512;
        const int t = f >> 5, c4 = (f & 31) << 2;
        xpre[i] = *(const short4v*)(x2b + (tb + t) * 128 + c4);
        *(short4v*)(xs + t * XSTR + c4) = xpre[i];
    }
    __syncthreads();

    // ---- QKV projection: wave w owns head w's q/k/v columns ----
    short8 af[3][4];
    #pragma unroll
    for (int mt = 0; mt < 3; ++mt)
        #pragma unroll
        for (int k = 0; k < 4; ++k)
            af[mt][k] = *(const short8*)(xs + (mt * 16 + l15) * XSTR + k * 32 + quad * 8);

    const int n0 = wave * 16 + l15;
    {
        const short* wp = wcat + ((wave + 8) * 16 + l15) * 128 + quad * 8;
        #pragma unroll
        for (int k = 0; k < 4; ++k) bnext[k] = *(const short8*)(wp + k * 32);
        floatx4 acc[3] = {{0,0,0,0},{0,0,0,0},{0,0,0,0}};
        #pragma unroll
        for (int mt = 0; mt < 3; ++mt)
            #pragma unroll
            for (int k = 0; k < 4; ++k)
                acc[mt] = __builtin_amdgcn_mfma_f32_16x16x32_bf16(af[mt][k], bcur[k], acc[mt], 0, 0, 0);
        #pragma unroll
        for (int mt = 0; mt < 3; ++mt) {
            const int rbase = mt * 16 + quad * 4;
            #pragma unroll
            for (int g = 0; g < 4; ++g)
                qs[(rbase + g) * XSTR + n0] = f2b(acc[mt][g] * 0.25f);
        }
    }
    {
        const short* wp = wcat + ((wave + 16) * 16 + l15) * 128 + quad * 8;
        #pragma unroll
        for (int k = 0; k < 4; ++k) bcur[k] = *(const short8*)(wp + k * 32);
        floatx4 acc[3] = {{0,0,0,0},{0,0,0,0},{0,0,0,0}};
        #pragma unroll
        for (int mt = 0; mt < 3; ++mt)
            #pragma unroll
            for (int k = 0; k < 4; ++k)
                acc[mt] = __builtin_amdgcn_mfma_f32_16x16x32_bf16(af[mt][k], bnext[k], acc[mt], 0, 0, 0);
        #pragma unroll
        for (int mt = 0; mt < 3; ++mt) {
            const int rbase = mt * 16 + quad * 4;
            #pragma unroll
            for (int g = 0; g < 4; ++g)
                ks[(rbase + g) * XSTR + n0] = f2b(acc[mt][g]);
        }
    }
    {
        floatx4 acc[3] = {{0,0,0,0},{0,0,0,0},{0,0,0,0}};
        #pragma unroll
        for (int mt = 0; mt < 3; ++mt)
            #pragma unroll
            for (int k = 0; k < 4; ++k)
                acc[mt] = __builtin_amdgcn_mfma_f32_16x16x32_bf16(af[mt][k], bcur[k], acc[mt], 0, 0, 0);
        #pragma unroll
        for (int mt = 0; mt < 3; ++mt) {
            short4v pk;
            #pragma unroll
            for (int g = 0; g < 4; ++g) pk[g] = f2b(acc[mt][g]);
            *(short4v*)(vs + n0 * VSTR + mt * 16 + quad * 4) = pk;
        }
    }

    // ---- attention, head = wave (no barrier: intra-wave LDS dependency) ----
    short* pbw = pb + wave * (16 * VSTR);
    const short8 Z8 = {0,0,0,0,0,0,0,0};
    const int hb = wave * 16;
    short8 bk[3], bv0, bv1;
    #pragma unroll
    for (int nt = 0; nt < 3; ++nt) {
        bk[nt] = Z8;
        if (quad < 2) bk[nt] = *(const short8*)(ks + (nt * 16 + l15) * XSTR + hb + quad * 8);
    }
    bv0 = *(const short8*)(vs + (hb + l15) * VSTR + quad * 8);
    bv1 = Z8;
    if (quad < 2) bv1 = *(const short8*)(vs + (hb + l15) * VSTR + 32 + quad * 8);

    #pragma unroll
    for (int mt = 0; mt < 3; ++mt) {
        short8 aq = Z8;
        if (quad < 2) aq = *(const short8*)(qs + (mt * 16 + l15) * XSTR + hb + quad * 8);
        floatx4 sc[3];
        #pragma unroll
        for (int nt = 0; nt < 3; ++nt) {
            floatx4 z = {0,0,0,0};
            sc[nt] = __builtin_amdgcn_mfma_f32_16x16x32_bf16(aq, bk[nt], z, 0, 0, 0);
        }
        #pragma unroll
        for (int g = 0; g < 4; ++g) {
            const float e0 = __expf(sc[0][g]);
            const float e1 = __expf(sc[1][g]);
            const float e2 = __expf(sc[2][g]);
            float ssum = e0 + e1 + e2;
            ssum += __shfl_xor(ssum, 1, 64);
            ssum += __shfl_xor(ssum, 2, 64);
            ssum += __shfl_xor(ssum, 4, 64);
            ssum += __shfl_xor(ssum, 8, 64);
            const float inv = 1.0f / ssum;
            short* prow = pbw + (quad * 4 + g) * VSTR;
            prow[l15]      = f2b(e0 * inv);
            prow[16 + l15] = f2b(e1 * inv);
            prow[32 + l15] = f2b(e2 * inv);
        }
        floatx4 o = {0,0,0,0};
        {
            short8 ap = *(const short8*)(pbw + l15 * VSTR + quad * 8);
            o = __builtin_amdgcn_mfma_f32_16x16x32_bf16(ap, bv0, o, 0, 0, 0);
            short8 ap1 = Z8;
            if (quad < 2) ap1 = *(const short8*)(pbw + l15 * VSTR + 32 + quad * 8);
            o = __builtin_amdgcn_mfma_f32_16x16x32_bf16(ap1, bv1, o, 0, 0, 0);
        }
        #pragma unroll
        for (int g = 0; g < 4; ++g)
            ob[(mt * 16 + quad * 4 + g) * XSTR + hb + l15] = f2b(o[g]);
    }
    __syncthreads();

    // ---- output projection -> xr (fp32, + bias); 1 ntile/wave ----
    #pragma unroll
    for (int mt = 0; mt < 3; ++mt)
        #pragma unroll
        for (int k = 0; k < 4; ++k)
            af[mt][k] = *(const short8*)(ob + (mt * 16 + l15) * XSTR + k * 32 + quad * 8);
    {
        const int n = wave * 16 + l15;
        short8 bf_[4];
        #pragma unroll
        for (int k = 0; k < 4; ++k)
            bf_[k] = *(const short8*)(woutb + n * 128 + k * 32 + quad * 8);
        floatx4 acc[3] = {{0,0,0,0},{0,0,0,0},{0,0,0,0}};
        #pragma unroll
        for (int mt = 0; mt < 3; ++mt)
            #pragma unroll
            for (int k = 0; k < 4; ++k)
                acc[mt] = __builtin_amdgcn_mfma_f32_16x16x32_bf16(af[mt][k], bf_[k], acc[mt], 0, 0, 0);
        const float bo = bout[n];
        #pragma unroll
        for (int mt = 0; mt < 3; ++mt)
            #pragma unroll
            for (int g = 0; g < 4; ++g)
                xr[(mt * 16 + quad * 4 + g) * MSTR + n] = acc[mt][g] + bo;
    }
    __syncthreads();

    // ---- residual + LN1 stats fused: each row lives in one half-wave ----
    #pragma unroll
    for (int i = 0; i < 3; ++i) {
        const int f = tid + i * 512;
        const int t = f >> 5, c4 = (f & 31) << 2;
        float s1 = 0.f, s2 = 0.f;
        #pragma unroll
        for (int j = 0; j < 4; ++j) {
            const float vv = xr[t * MSTR + c4 + j] + b2f(apre[i][j]) + b2f(xpre[i][j]);
            xr[t * MSTR + c4 + j] = vv;
            s1 += vv; s2 += vv * vv;
        }
        s1 += __shfl_xor(s1, 1, 64);  s2 += __shfl_xor(s2, 1, 64);
        s1 += __shfl_xor(s1, 2, 64);  s2 += __shfl_xor(s2, 2, 64);
        s1 += __shfl_xor(s1, 4, 64);  s2 += __shfl_xor(s2, 4, 64);
        s1 += __shfl_xor(s1, 8, 64);  s2 += __shfl_xor(s2, 8, 64);
        s1 += __shfl_xor(s1, 16, 64); s2 += __shfl_xor(s2, 16, 64);
        if ((lane & 31) == 0) {
            const float m = s1 * (1.f / 128.f);
            mean_[t] = m;
            rstd_[t] = rsqrtf(s2 * (1.f / 128.f) - m * m + 1e-5f);
        }
    }
    __syncthreads();

    for (int f = tid; f < 6144; f += 512) {
        const int t = f >> 7, c = f & 127;
        lnb[t * XSTR + c] = f2b((xr[t * MSTR + c] - mean_[t]) * rstd_[t] * gs[c] + bs[c]);
    }
    __syncthreads();

    // ---- MLP GEMM1 + relu ----
    #pragma unroll
    for (int mt = 0; mt < 3; ++mt)
        #pragma unroll
        for (int k = 0; k < 4; ++k)
            af[mt][k] = *(const short8*)(lnb + (mt * 16 + l15) * XSTR + k * 32 + quad * 8);
    {
        const int n = wave * 16 + l15;
        short8 bf_[4];
        #pragma unroll
        for (int k = 0; k < 4; ++k)
            bf_[k] = *(const short8*)(w1b + n * 128 + k * 32 + quad * 8);
        floatx4 acc[3] = {{0,0,0,0},{0,0,0,0},{0,0,0,0}};
        #pragma unroll
        for (int mt = 0; mt < 3; ++mt)
            #pragma unroll
            for (int k = 0; k < 4; ++k)
                acc[mt] = __builtin_amdgcn_mfma_f32_16x16x32_bf16(af[mt][k], bf_[k], acc[mt], 0, 0, 0);
        const float bb = b1s[n];
        #pragma unroll
        for (int mt = 0; mt < 3; ++mt)
            #pragma unroll
            for (int g = 0; g < 4; ++g)
                hbuf[(mt * 16 + quad * 4 + g) * XSTR + n] = f2b(fmaxf(acc[mt][g] + bb, 0.f));
    }
    __syncthreads();

    // ---- MLP GEMM2 + inner residual (fp32-recomputed ln1) ----
    #pragma unroll
    for (int mt = 0; mt < 3; ++mt)
        #pragma unroll
        for (int k = 0; k < 4; ++k)
            af[mt][k] = *(const short8*)(hbuf + (mt * 16 + l15) * XSTR + k * 32 + quad * 8);
    {
        const int n = wave * 16 + l15;
        short8 bf_[4];
        #pragma unroll
        for (int k = 0; k < 4; ++k)
            bf_[k] = *(const short8*)(w2b + n * 128 + k * 32 + quad * 8);
        floatx4 acc[3] = {{0,0,0,0},{0,0,0,0},{0,0,0,0}};
        #pragma unroll
        for (int mt = 0; mt < 3; ++mt)
            #pragma unroll
            for (int k = 0; k < 4; ++k)
                acc[mt] = __builtin_amdgcn_mfma_f32_16x16x32_bf16(af[mt][k], bf_[k], acc[mt], 0, 0, 0);
        const float bb = b2s[n];
        #pragma unroll
        for (int mt = 0; mt < 3; ++mt)
            #pragma unroll
            for (int g = 0; g < 4; ++g) {
                const int t = mt * 16 + quad * 4 + g;
                const float ln1 = (xr[t * MSTR + n] - mean_[t]) * rstd_[t] * gs[n] + bs[n];
                xr[t * MSTR + n] = acc[mt][g] + bb + ln1;
            }
    }
    __syncthreads();
    ln_stats129(xr, mean_, rstd_, tid);
    __syncthreads();

    // ---- channels-first vectorized output ----
    for (int f = tid; f < 1536; f += 512) {
        const int c = f / 12, z4 = (f % 12) * 4;
        floatx4 o4;
        #pragma unroll
        for (int j = 0; j < 4; ++j)
            o4[j] = (xr[(z4 + j) * MSTR + c] - mean_[z4 + j]) * rstd_[z4 + j] * gs[c] + bs[c];
        *(floatx4*)(out + (long)(b * 128 + c) * 110592 + xx * 2304 + yy * 48 + z4) = o4;
    }
}

// -------------------------------------------------------------------------------------
extern "C" void kernel_launch(void* const* d_in, const int* in_sizes, int n_in,
                              void* d_out, int out_size, void* d_ws, size_t ws_size,
                              hipStream_t stream)
{
    const float* x    = (const float*)d_in[0];
    const float* px   = (const float*)d_in[1];
    const float* py   = (const float*)d_in[2];
    const float* pz   = (const float*)d_in[3];
    const float* wq[3]   = { (const float*)d_in[4],  (const float*)d_in[8],  (const float*)d_in[12] };
    const float* wkv[3]  = { (const float*)d_in[5],  (const float*)d_in[9],  (const float*)d_in[13] };
    const float* wout[3] = { (const float*)d_in[6],  (const float*)d_in[10], (const float*)d_in[14] };
    const float* bout[3] = { (const float*)d_in[7],  (const float*)d_in[11], (const float*)d_in[15] };
    const float* ln_g = (const float*)d_in[16];
    const float* ln_b = (const float*)d_in[17];
    const float* w1   = (const float*)d_in[18];
    const float* b1   = (const float*)d_in[19];
    const float* w2   = (const float*)d_in[20];
    const float* b2   = (const float*)d_in[21];

    // ws: A bf16 (56,623,104 B) | weights bf16 (458,752 B) | x2b bf16 (56,623,104 B)
    short* Ab  = (short*)d_ws;
    short* wb  = (short*)((char*)d_ws + 56623104);
    short* x2b = (short*)((char*)d_ws + 57081856);

    prep_weights<<<896, 256, 0, stream>>>(wq[0], wkv[0], wq[1], wkv[1], wq[2], wkv[2],
                                          wout[0], wout[1], wout[2], w1, w2, wb);
    prep_x2<<<4608, 256, 0, stream>>>(x, px, py, pz, x2b);

    attn_axis<0, 0><<<4608, 512, 0, stream>>>(x2b, wb,         wb + 147456, bout[0], Ab);
    attn_axis<1, 1><<<4608, 512, 0, stream>>>(x2b, wb + 49152, wb + 163840, bout[1], Ab);

    attn2_mlp<<<4608, 512, 0, stream>>>(x2b, Ab, wb + 98304, wb + 180224, bout[2],
                                        ln_g, ln_b, wb + 196608, b1, wb + 212992, b2,
                                        (float*)d_out);
}

// Round 4
// 575.045 us; speedup vs baseline: 1.3294x; 1.0462x over previous
//
#include <hip/hip_runtime.h>
#include <hip/hip_bf16.h>

typedef __attribute__((ext_vector_type(8))) short short8;
typedef __attribute__((ext_vector_type(4))) short short4v;
typedef __attribute__((ext_vector_type(4))) float floatx4;

#define XSTR 136   // bf16 token-major tile stride (272B rows, 16B-aligned)
#define HSTR 16    // per-head token-major Q/K stride (32B rows, no pad)
#define VSTR 56    // bf16 V^T / P stride (112B rows, 16B-aligned)
#define SSTR 132   // fp32 out-stage stride (16B-aligned rows)
#define MSTR 132   // fp32 xr stride in fused kernel (16B-aligned rows)

static __device__ __forceinline__ short f2b(float f) {
    __hip_bfloat16 h = __float2bfloat16(f);
    return *reinterpret_cast<short*>(&h);
}
static __device__ __forceinline__ float b2f(short s) {
    unsigned int u = ((unsigned int)(unsigned short)s) << 16;
    return __uint_as_float(u);
}

// ---------------- weight cast (keeps [n][k] row-major = MFMA A/B-operand layout) -----
__global__ __launch_bounds__(256) void prep_weights(
    const float* __restrict__ wq0, const float* __restrict__ wkv0,
    const float* __restrict__ wq1, const float* __restrict__ wkv1,
    const float* __restrict__ wq2, const float* __restrict__ wkv2,
    const float* __restrict__ wout0, const float* __restrict__ wout1,
    const float* __restrict__ wout2, const float* __restrict__ w1,
    const float* __restrict__ w2, short* __restrict__ dst)
{
    const int g = blockIdx.x * 256 + threadIdx.x;  // grid exactly covers 229376
    const float* wqs[3]  = { wq0, wq1, wq2 };
    const float* wkvs[3] = { wkv0, wkv1, wkv2 };
    const float* rest[5] = { wout0, wout1, wout2, w1, w2 };
    float val;
    if (g < 147456) {
        const int a = g / 49152, l = g % 49152;
        val = (l < 16384) ? wqs[a][l] : wkvs[a][l - 16384];
    } else {
        const int l = g - 147456;
        val = rest[l >> 14][l & 16383];
    }
    dst[g] = f2b(val);
}

// ---------------- x2 = 2x + px + py + pz, channels-last bf16 -------------------------
__global__ __launch_bounds__(256) void prep_x2(
    const float* __restrict__ x, const float* __restrict__ px,
    const float* __restrict__ py, const float* __restrict__ pz,
    short* __restrict__ x2b)
{
    __shared__ float tile[128 * 49];
    const int s = blockIdx.x, tid = threadIdx.x;
    const int b = s / 2304, rr = s % 2304, xx = rr / 48, yy = rr % 48;
    for (int f = tid; f < 1536; f += 256) {
        const int c = f / 12, z4 = (f % 12) * 4;
        const floatx4 xv = *(const floatx4*)(x + (long)(b * 128 + c) * 110592 + xx * 2304 + yy * 48 + z4);
        const float pxy = px[c * 48 + xx] + py[c * 48 + yy];
        #pragma unroll
        for (int j = 0; j < 4; ++j)
            tile[c * 49 + z4 + j] = 2.0f * xv[j] + pxy + pz[c * 48 + z4 + j];
    }
    __syncthreads();
    const long tb = (long)b * 110592 + xx * 2304 + yy * 48;
    for (int f = tid; f < 1536; f += 256) {
        const int t = f >> 5, c4 = (f & 31) << 2;
        short4v pk;
        #pragma unroll
        for (int j = 0; j < 4; ++j) pk[j] = f2b(tile[(c4 + j) * 49 + t]);
        *(short4v*)(x2b + (tb + t) * 128 + c4) = pk;
    }
}

// ---------------- MFMA axial attention (axes 0/1), 512 threads / 8 waves --------------
// wave=head. All GEMMs except V use swapped operands (weights as A-frag) so the MFMA
// C-layout packs into b64 stores: no scalar LDS stores anywhere. Scores computed as S^T
// (lane = query token) -> softmax is 11 in-reg adds + 2 shuffles, P^T packs b64.
template<int AXIS, int ACC>
__global__ __launch_bounds__(512, 4)
void attn_axis(const short* __restrict__ x2b, const short* __restrict__ wcat,
               const short* __restrict__ woutb, const float* __restrict__ bout,
               short* __restrict__ Ab)
{
    __shared__ __align__(16) char SM[79360];
    short* xs  = (short*)SM;              // [48][XSTR] x2 tile
    short* qsT = (short*)(SM + 13056);    // 8 heads x [48][HSTR]  (12288)
    short* ksT = (short*)(SM + 25344);    // 8 heads x [48][HSTR]  (12288)
    short* vs  = (short*)(SM + 37632);    // [128][VSTR] V^T       (14336)
    short* pb  = (short*)(SM + 51968);    // 8 waves x [16][VSTR]  (14336)
    short* obT = (short*)(SM + 66304);    // [48][XSTR] O tile     (13056)
    float* stg = (float*)(SM + 13056);    // [48][SSTR] fp32 out stage (aliases qsT/ksT/vs-head)

    const int tid  = threadIdx.x;
    const int lane = tid & 63;
    const int wave = tid >> 6;            // 0..7 == head
    const int l15  = lane & 15;
    const int quad = lane >> 4;

    const int s = blockIdx.x;
    const int b = s / 2304, rr = s % 2304, u = rr / 48, v = rr % 48;
    long base; int stride;
    if (AXIS == 0) { base = (long)b * 110592 + u * 48   + v; stride = 2304; }
    else           { base = (long)b * 110592 + u * 2304 + v; stride = 48;   }

    // ---- prefetch A for the RMW (consumed at the very end) ----
    short4v apre[3];
    if (ACC) {
        #pragma unroll
        for (int i = 0; i < 3; ++i) {
            const int f = tid + i * 512;
            const int t = f >> 5, c4 = (f & 31) << 2;
            apre[i] = *(const short4v*)(Ab + (base + (long)t * stride) * 128 + c4);
        }
    }
    // ---- prefetch Q weight frags (rows wave*16..) ----
    short8 wq_[4], wk_[4], wv_[4];
    {
        const short* wp = wcat + (wave * 16 + l15) * 128 + quad * 8;
        #pragma unroll
        for (int k = 0; k < 4; ++k) wq_[k] = *(const short8*)(wp + k * 32);
    }

    // ---- stage x2 tile ----
    for (int f = tid; f < 1536; f += 512) {
        const int t = f >> 5, c4 = (f & 31) << 2;
        *(short4v*)(xs + t * XSTR + c4) =
            *(const short4v*)(x2b + (base + (long)t * stride) * 128 + c4);
    }
    __syncthreads();

    // ---- token B-frags (usable as A or B operand: identical lane mapping) ----
    short8 af[3][4];
    #pragma unroll
    for (int ct = 0; ct < 3; ++ct)
        #pragma unroll
        for (int k = 0; k < 4; ++k)
            af[ct][k] = *(const short8*)(xs + (ct * 16 + l15) * XSTR + k * 32 + quad * 8);

    short* qw  = qsT + wave * (48 * HSTR);
    short* kw  = ksT + wave * (48 * HSTR);
    const int hb = wave * 16;

    // ---- Q (swapped): C[feat,token] -> packed b64 token-major; prefetch K weights ----
    {
        const short* wp = wcat + ((wave + 8) * 16 + l15) * 128 + quad * 8;
        #pragma unroll
        for (int k = 0; k < 4; ++k) wk_[k] = *(const short8*)(wp + k * 32);
        floatx4 acc[3] = {{0,0,0,0},{0,0,0,0},{0,0,0,0}};
        #pragma unroll
        for (int ct = 0; ct < 3; ++ct)
            #pragma unroll
            for (int k = 0; k < 4; ++k)
                acc[ct] = __builtin_amdgcn_mfma_f32_16x16x32_bf16(wq_[k], af[ct][k], acc[ct], 0, 0, 0);
        #pragma unroll
        for (int ct = 0; ct < 3; ++ct) {
            short4v pk;
            #pragma unroll
            for (int g = 0; g < 4; ++g) pk[g] = f2b(acc[ct][g] * 0.25f);
            *(short4v*)(qw + (ct * 16 + l15) * HSTR + quad * 4) = pk;
        }
    }
    // ---- K (swapped); prefetch V weights ----
    {
        const short* wp = wcat + ((wave + 16) * 16 + l15) * 128 + quad * 8;
        #pragma unroll
        for (int k = 0; k < 4; ++k) wv_[k] = *(const short8*)(wp + k * 32);
        floatx4 acc[3] = {{0,0,0,0},{0,0,0,0},{0,0,0,0}};
        #pragma unroll
        for (int ct = 0; ct < 3; ++ct)
            #pragma unroll
            for (int k = 0; k < 4; ++k)
                acc[ct] = __builtin_amdgcn_mfma_f32_16x16x32_bf16(wk_[k], af[ct][k], acc[ct], 0, 0, 0);
        #pragma unroll
        for (int ct = 0; ct < 3; ++ct) {
            short4v pk;
            #pragma unroll
            for (int g = 0; g < 4; ++g) pk[g] = f2b(acc[ct][g]);
            *(short4v*)(kw + (ct * 16 + l15) * HSTR + quad * 4) = pk;
        }
    }
    // ---- V (original): C[token,feat], lane col = feature -> feature-major packed ----
    {
        floatx4 acc[3] = {{0,0,0,0},{0,0,0,0},{0,0,0,0}};
        #pragma unroll
        for (int mt = 0; mt < 3; ++mt)
            #pragma unroll
            for (int k = 0; k < 4; ++k)
                acc[mt] = __builtin_amdgcn_mfma_f32_16x16x32_bf16(af[mt][k], wv_[k], acc[mt], 0, 0, 0);
        #pragma unroll
        for (int mt = 0; mt < 3; ++mt) {
            short4v pk;
            #pragma unroll
            for (int g = 0; g < 4; ++g) pk[g] = f2b(acc[mt][g]);
            *(short4v*)(vs + (hb + l15) * VSTR + mt * 16 + quad * 4) = pk;
        }
    }

    // ---- attention (intra-wave, no barrier): S^T = mfma(K, Q) ----
    short* pbw = pb + wave * (16 * VSTR);
    const short8 Z8 = {0,0,0,0,0,0,0,0};
    short8 akf[3], aqf[3];
    #pragma unroll
    for (int t = 0; t < 3; ++t) {
        akf[t] = (quad < 2) ? *(const short8*)(kw + (t * 16 + l15) * HSTR + quad * 8) : Z8;
        aqf[t] = (quad < 2) ? *(const short8*)(qw + (t * 16 + l15) * HSTR + quad * 8) : Z8;
    }
    short8 av0 = *(const short8*)(vs + (hb + l15) * VSTR + quad * 8);
    short8 av1 = (quad < 2) ? *(const short8*)(vs + (hb + l15) * VSTR + 32 + quad * 8) : Z8;

    #pragma unroll
    for (int it = 0; it < 3; ++it) {
        floatx4 sc[3];
        #pragma unroll
        for (int jt = 0; jt < 3; ++jt) {
            floatx4 z = {0,0,0,0};
            sc[jt] = __builtin_amdgcn_mfma_f32_16x16x32_bf16(akf[jt], aqf[it], z, 0, 0, 0);
        }
        // softmax over j (rows): 12 in-register + cross-quad shuffles; no max-shift
        float e[3][4]; float ssum = 0.f;
        #pragma unroll
        for (int jt = 0; jt < 3; ++jt)
            #pragma unroll
            for (int g = 0; g < 4; ++g) { e[jt][g] = __expf(sc[jt][g]); ssum += e[jt][g]; }
        ssum += __shfl_xor(ssum, 16, 64);
        ssum += __shfl_xor(ssum, 32, 64);
        const float inv = 1.0f / ssum;
        #pragma unroll
        for (int jt = 0; jt < 3; ++jt) {
            short4v pk;
            #pragma unroll
            for (int g = 0; g < 4; ++g) pk[g] = f2b(e[jt][g] * inv);
            *(short4v*)(pbw + l15 * VSTR + jt * 16 + quad * 4) = pk;
        }
        // PV (swapped): O^T[feat, token] = mfma(V^T-frag, P-frag)
        short8 ap  = *(const short8*)(pbw + l15 * VSTR + quad * 8);
        short8 ap1 = (quad < 2) ? *(const short8*)(pbw + l15 * VSTR + 32 + quad * 8) : Z8;
        floatx4 o = {0,0,0,0};
        o = __builtin_amdgcn_mfma_f32_16x16x32_bf16(av0, ap,  o, 0, 0, 0);
        o = __builtin_amdgcn_mfma_f32_16x16x32_bf16(av1, ap1, o, 0, 0, 0);
        short4v ok;
        #pragma unroll
        for (int g = 0; g < 4; ++g) ok[g] = f2b(o[g]);
        *(short4v*)(obT + (it * 16 + l15) * XSTR + hb + quad * 4) = ok;
    }
    __syncthreads();

    // ---- output projection (swapped): C[outfeat, token] -> vectorized stg ----
    short8 afo[3][4];
    #pragma unroll
    for (int ct = 0; ct < 3; ++ct)
        #pragma unroll
        for (int k = 0; k < 4; ++k)
            afo[ct][k] = *(const short8*)(obT + (ct * 16 + l15) * XSTR + k * 32 + quad * 8);
    {
        const int nf = wave * 16;
        short8 wo_[4];
        #pragma unroll
        for (int k = 0; k < 4; ++k)
            wo_[k] = *(const short8*)(woutb + (nf + l15) * 128 + k * 32 + quad * 8);
        floatx4 acc[3] = {{0,0,0,0},{0,0,0,0},{0,0,0,0}};
        #pragma unroll
        for (int ct = 0; ct < 3; ++ct)
            #pragma unroll
            for (int k = 0; k < 4; ++k)
                acc[ct] = __builtin_amdgcn_mfma_f32_16x16x32_bf16(wo_[k], afo[ct][k], acc[ct], 0, 0, 0);
        const floatx4 bo4 = *(const floatx4*)(bout + nf + quad * 4);
        #pragma unroll
        for (int ct = 0; ct < 3; ++ct) {
            floatx4 ox;
            #pragma unroll
            for (int g = 0; g < 4; ++g) ox[g] = acc[ct][g] + bo4[g];
            *(floatx4*)(stg + (ct * 16 + l15) * SSTR + nf + quad * 4) = ox;
        }
    }
    __syncthreads();

    // ---- coalesced write / RMW into bf16 A ----
    #pragma unroll
    for (int i = 0; i < 3; ++i) {
        const int f = tid + i * 512;
        const int t = f >> 5, c4 = (f & 31) << 2;
        const long gi = (base + (long)t * stride) * 128 + c4;
        const floatx4 vv = *(const floatx4*)(stg + t * SSTR + c4);
        short4v out4;
        if (ACC) {
            #pragma unroll
            for (int j = 0; j < 4; ++j) out4[j] = f2b(b2f(apre[i][j]) + vv[j]);
        } else {
            #pragma unroll
            for (int j = 0; j < 4; ++j) out4[j] = f2b(vv[j]);
        }
        *(short4v*)(Ab + gi) = out4;
    }
}

// ---------------- fused axis-2 attention + residual + LN1 + MLP + LN2 + out -----------
// LN2 stats: per-lane rotation breaks the p-invariant bank collision (stride 132).
static __device__ __forceinline__ void ln_stats132(const float* xr, float* mean_,
                                                   float* rstd_, int tid)
{
    if (tid < 192) {
        const int r = tid >> 2, p = tid & 3;
        const float* row = xr + r * MSTR + p * 32;
        float s1 = 0.f, s2 = 0.f;
        #pragma unroll
        for (int c0 = 0; c0 < 32; ++c0) {
            const float xv = row[(c0 + p * 8) & 31];
            s1 += xv; s2 += xv * xv;
        }
        s1 += __shfl_xor(s1, 1, 64); s1 += __shfl_xor(s1, 2, 64);
        s2 += __shfl_xor(s2, 1, 64); s2 += __shfl_xor(s2, 2, 64);
        if (p == 0) {
            const float m = s1 * (1.f / 128.f);
            mean_[r] = m;
            rstd_[r] = rsqrtf(s2 * (1.f / 128.f) - m * m + 1e-5f);
        }
    }
}

__global__ __launch_bounds__(512, 4)
void attn2_mlp(const short* __restrict__ x2b, const short* __restrict__ Ab,
               const short* __restrict__ wcat, const short* __restrict__ woutb,
               const float* __restrict__ bout,
               const float* __restrict__ ln_g, const float* __restrict__ ln_b,
               const short* __restrict__ w1b, const float* __restrict__ b1,
               const short* __restrict__ w2b, const float* __restrict__ b2,
               float* __restrict__ out)
{
    __shared__ __align__(16) char SM[81792];
    short* xs   = (short*)SM;              // [48][XSTR] x2 stage
    short* qsT  = (short*)(SM + 13056);    // 12288
    short* ksT  = (short*)(SM + 25344);    // 12288
    short* vs   = (short*)(SM + 37632);    // 14336
    short* pb   = (short*)(SM + 51968);    // 14336
    short* obT  = (short*)(SM + 66304);    // 13056; later hbuf
    float* xr   = (float*)(SM + 13056);    // [48][MSTR] fp32, 25344 (aliases qsT/ksT/vs-head)
    short* lnb  = (short*)(SM + 38400);    // 13056 (aliases vs tail + pb head; both dead)
    short* hbuf = (short*)(SM + 66304);    // aliases obT
    float* gs   = (float*)(SM + 79360);
    float* bs   = (float*)(SM + 79872);
    float* b1s  = (float*)(SM + 80384);
    float* b2s  = (float*)(SM + 80896);
    float* mean_ = (float*)(SM + 81408);
    float* rstd_ = (float*)(SM + 81600);

    const int tid  = threadIdx.x;
    const int lane = tid & 63;
    const int wave = tid >> 6;             // 0..7 == head
    const int l15  = lane & 15;
    const int quad = lane >> 4;

    const int s = blockIdx.x;
    const int b = s / 2304, rr = s % 2304, xx = rr / 48, yy = rr % 48;
    const long tb = (long)b * 110592 + xx * 2304 + yy * 48;

    // ---- prefetch attention-sum A (consumed in residual) ----
    short4v apre[3];
    #pragma unroll
    for (int i = 0; i < 3; ++i) {
        const int f = tid + i * 512;
        const int t = f >> 5, c4 = (f & 31) << 2;
        apre[i] = *(const short4v*)(Ab + (tb + t) * 128 + c4);
    }
    // ---- prefetch Q weight frags ----
    short8 wq_[4], wk_[4], wv_[4];
    {
        const short* wp = wcat + (wave * 16 + l15) * 128 + quad * 8;
        #pragma unroll
        for (int k = 0; k < 4; ++k) wq_[k] = *(const short8*)(wp + k * 32);
    }

    if (tid < 128) {
        gs[tid] = ln_g[tid]; bs[tid] = ln_b[tid];
        b1s[tid] = b1[tid];  b2s[tid] = b2[tid];
    }
    // ---- stage x2 tile; keep values in registers for the residual ----
    short4v xpre[3];
    #pragma unroll
    for (int i = 0; i < 3; ++i) {
        const int f = tid + i * 512;
        const int t = f >> 5, c4 = (f & 31) << 2;
        xpre[i] = *(const short4v*)(x2b + (tb + t) * 128 + c4);
        *(short4v*)(xs + t * XSTR + c4) = xpre[i];
    }
    __syncthreads();

    // ---- token frags ----
    short8 af[3][4];
    #pragma unroll
    for (int ct = 0; ct < 3; ++ct)
        #pragma unroll
        for (int k = 0; k < 4; ++k)
            af[ct][k] = *(const short8*)(xs + (ct * 16 + l15) * XSTR + k * 32 + quad * 8);

    short* qw  = qsT + wave * (48 * HSTR);
    short* kw  = ksT + wave * (48 * HSTR);
    const int hb = wave * 16;

    // ---- Q (swapped) ----
    {
        const short* wp = wcat + ((wave + 8) * 16 + l15) * 128 + quad * 8;
        #pragma unroll
        for (int k = 0; k < 4; ++k) wk_[k] = *(const short8*)(wp + k * 32);
        floatx4 acc[3] = {{0,0,0,0},{0,0,0,0},{0,0,0,0}};
        #pragma unroll
        for (int ct = 0; ct < 3; ++ct)
            #pragma unroll
            for (int k = 0; k < 4; ++k)
                acc[ct] = __builtin_amdgcn_mfma_f32_16x16x32_bf16(wq_[k], af[ct][k], acc[ct], 0, 0, 0);
        #pragma unroll
        for (int ct = 0; ct < 3; ++ct) {
            short4v pk;
            #pragma unroll
            for (int g = 0; g < 4; ++g) pk[g] = f2b(acc[ct][g] * 0.25f);
            *(short4v*)(qw + (ct * 16 + l15) * HSTR + quad * 4) = pk;
        }
    }
    // ---- K (swapped) ----
    {
        const short* wp = wcat + ((wave + 16) * 16 + l15) * 128 + quad * 8;
        #pragma unroll
        for (int k = 0; k < 4; ++k) wv_[k] = *(const short8*)(wp + k * 32);
        floatx4 acc[3] = {{0,0,0,0},{0,0,0,0},{0,0,0,0}};
        #pragma unroll
        for (int ct = 0; ct < 3; ++ct)
            #pragma unroll
            for (int k = 0; k < 4; ++k)
                acc[ct] = __builtin_amdgcn_mfma_f32_16x16x32_bf16(wk_[k], af[ct][k], acc[ct], 0, 0, 0);
        #pragma unroll
        for (int ct = 0; ct < 3; ++ct) {
            short4v pk;
            #pragma unroll
            for (int g = 0; g < 4; ++g) pk[g] = f2b(acc[ct][g]);
            *(short4v*)(kw + (ct * 16 + l15) * HSTR + quad * 4) = pk;
        }
    }
    // ---- V (original) ----
    {
        floatx4 acc[3] = {{0,0,0,0},{0,0,0,0},{0,0,0,0}};
        #pragma unroll
        for (int mt = 0; mt < 3; ++mt)
            #pragma unroll
            for (int k = 0; k < 4; ++k)
                acc[mt] = __builtin_amdgcn_mfma_f32_16x16x32_bf16(af[mt][k], wv_[k], acc[mt], 0, 0, 0);
        #pragma unroll
        for (int mt = 0; mt < 3; ++mt) {
            short4v pk;
            #pragma unroll
            for (int g = 0; g < 4; ++g) pk[g] = f2b(acc[mt][g]);
            *(short4v*)(vs + (hb + l15) * VSTR + mt * 16 + quad * 4) = pk;
        }
    }

    // ---- attention (intra-wave, no barrier) ----
    short* pbw = pb + wave * (16 * VSTR);
    const short8 Z8 = {0,0,0,0,0,0,0,0};
    short8 akf[3], aqf[3];
    #pragma unroll
    for (int t = 0; t < 3; ++t) {
        akf[t] = (quad < 2) ? *(const short8*)(kw + (t * 16 + l15) * HSTR + quad * 8) : Z8;
        aqf[t] = (quad < 2) ? *(const short8*)(qw + (t * 16 + l15) * HSTR + quad * 8) : Z8;
    }
    short8 av0 = *(const short8*)(vs + (hb + l15) * VSTR + quad * 8);
    short8 av1 = (quad < 2) ? *(const short8*)(vs + (hb + l15) * VSTR + 32 + quad * 8) : Z8;

    #pragma unroll
    for (int it = 0; it < 3; ++it) {
        floatx4 sc[3];
        #pragma unroll
        for (int jt = 0; jt < 3; ++jt) {
            floatx4 z = {0,0,0,0};
            sc[jt] = __builtin_amdgcn_mfma_f32_16x16x32_bf16(akf[jt], aqf[it], z, 0, 0, 0);
        }
        float e[3][4]; float ssum = 0.f;
        #pragma unroll
        for (int jt = 0; jt < 3; ++jt)
            #pragma unroll
            for (int g = 0; g < 4; ++g) { e[jt][g] = __expf(sc[jt][g]); ssum += e[jt][g]; }
        ssum += __shfl_xor(ssum, 16, 64);
        ssum += __shfl_xor(ssum, 32, 64);
        const float inv = 1.0f / ssum;
        #pragma unroll
        for (int jt = 0; jt < 3; ++jt) {
            short4v pk;
            #pragma unroll
            for (int g = 0; g < 4; ++g) pk[g] = f2b(e[jt][g] * inv);
            *(short4v*)(pbw + l15 * VSTR + jt * 16 + quad * 4) = pk;
        }
        short8 ap  = *(const short8*)(pbw + l15 * VSTR + quad * 8);
        short8 ap1 = (quad < 2) ? *(const short8*)(pbw + l15 * VSTR + 32 + quad * 8) : Z8;
        floatx4 o = {0,0,0,0};
        o = __builtin_amdgcn_mfma_f32_16x16x32_bf16(av0, ap,  o, 0, 0, 0);
        o = __builtin_amdgcn_mfma_f32_16x16x32_bf16(av1, ap1, o, 0, 0, 0);
        short4v ok;
        #pragma unroll
        for (int g = 0; g < 4; ++g) ok[g] = f2b(o[g]);
        *(short4v*)(obT + (it * 16 + l15) * XSTR + hb + quad * 4) = ok;
    }
    __syncthreads();

    const int nf = wave * 16;
    // ---- output projection (swapped) -> xr fp32 vectorized ----
    {
        short8 afo[3][4];
        #pragma unroll
        for (int ct = 0; ct < 3; ++ct)
            #pragma unroll
            for (int k = 0; k < 4; ++k)
                afo[ct][k] = *(const short8*)(obT + (ct * 16 + l15) * XSTR + k * 32 + quad * 8);
        short8 wo_[4];
        #pragma unroll
        for (int k = 0; k < 4; ++k)
            wo_[k] = *(const short8*)(woutb + (nf + l15) * 128 + k * 32 + quad * 8);
        floatx4 acc[3] = {{0,0,0,0},{0,0,0,0},{0,0,0,0}};
        #pragma unroll
        for (int ct = 0; ct < 3; ++ct)
            #pragma unroll
            for (int k = 0; k < 4; ++k)
                acc[ct] = __builtin_amdgcn_mfma_f32_16x16x32_bf16(wo_[k], afo[ct][k], acc[ct], 0, 0, 0);
        const floatx4 bo4 = *(const floatx4*)(bout + nf + quad * 4);
        #pragma unroll
        for (int ct = 0; ct < 3; ++ct) {
            floatx4 ox;
            #pragma unroll
            for (int g = 0; g < 4; ++g) ox[g] = acc[ct][g] + bo4[g];
            *(floatx4*)(xr + (ct * 16 + l15) * MSTR + nf + quad * 4) = ox;
        }
    }
    __syncthreads();

    // ---- residual + LN1 stats fused: each row lives in one half-wave ----
    #pragma unroll
    for (int i = 0; i < 3; ++i) {
        const int f = tid + i * 512;
        const int t = f >> 5, c4 = (f & 31) << 2;
        floatx4 xv = *(const floatx4*)(xr + t * MSTR + c4);
        float s1 = 0.f, s2 = 0.f;
        #pragma unroll
        for (int j = 0; j < 4; ++j) {
            xv[j] += b2f(apre[i][j]) + b2f(xpre[i][j]);
            s1 += xv[j]; s2 += xv[j] * xv[j];
        }
        *(floatx4*)(xr + t * MSTR + c4) = xv;
        s1 += __shfl_xor(s1, 1, 64);  s2 += __shfl_xor(s2, 1, 64);
        s1 += __shfl_xor(s1, 2, 64);  s2 += __shfl_xor(s2, 2, 64);
        s1 += __shfl_xor(s1, 4, 64);  s2 += __shfl_xor(s2, 4, 64);
        s1 += __shfl_xor(s1, 8, 64);  s2 += __shfl_xor(s2, 8, 64);
        s1 += __shfl_xor(s1, 16, 64); s2 += __shfl_xor(s2, 16, 64);
        if ((lane & 31) == 0) {
            const float m = s1 * (1.f / 128.f);
            mean_[t] = m;
            rstd_[t] = rsqrtf(s2 * (1.f / 128.f) - m * m + 1e-5f);
        }
    }
    __syncthreads();

    for (int f = tid; f < 6144; f += 512) {
        const int t = f >> 7, c = f & 127;
        lnb[t * XSTR + c] = f2b((xr[t * MSTR + c] - mean_[t]) * rstd_[t] * gs[c] + bs[c]);
    }
    __syncthreads();

    // ---- MLP GEMM1 (swapped) + relu -> hbuf packed ----
    {
        short8 afl[3][4];
        #pragma unroll
        for (int ct = 0; ct < 3; ++ct)
            #pragma unroll
            for (int k = 0; k < 4; ++k)
                afl[ct][k] = *(const short8*)(lnb + (ct * 16 + l15) * XSTR + k * 32 + quad * 8);
        short8 w1_[4];
        #pragma unroll
        for (int k = 0; k < 4; ++k)
            w1_[k] = *(const short8*)(w1b + (nf + l15) * 128 + k * 32 + quad * 8);
        floatx4 acc[3] = {{0,0,0,0},{0,0,0,0},{0,0,0,0}};
        #pragma unroll
        for (int ct = 0; ct < 3; ++ct)
            #pragma unroll
            for (int k = 0; k < 4; ++k)
                acc[ct] = __builtin_amdgcn_mfma_f32_16x16x32_bf16(w1_[k], afl[ct][k], acc[ct], 0, 0, 0);
        const floatx4 bb4 = *(const floatx4*)(b1s + nf + quad * 4);
        #pragma unroll
        for (int ct = 0; ct < 3; ++ct) {
            short4v hk;
            #pragma unroll
            for (int g = 0; g < 4; ++g) hk[g] = f2b(fmaxf(acc[ct][g] + bb4[g], 0.f));
            *(short4v*)(hbuf + (ct * 16 + l15) * XSTR + nf + quad * 4) = hk;
        }
    }
    __syncthreads();

    // ---- MLP GEMM2 (swapped) + inner residual (fp32-recomputed ln1), vectorized ----
    {
        short8 afh[3][4];
        #pragma unroll
        for (int ct = 0; ct < 3; ++ct)
            #pragma unroll
            for (int k = 0; k < 4; ++k)
                afh[ct][k] = *(const short8*)(hbuf + (ct * 16 + l15) * XSTR + k * 32 + quad * 8);
        short8 w2_[4];
        #pragma unroll
        for (int k = 0; k < 4; ++k)
            w2_[k] = *(const short8*)(w2b + (nf + l15) * 128 + k * 32 + quad * 8);
        floatx4 acc[3] = {{0,0,0,0},{0,0,0,0},{0,0,0,0}};
        #pragma unroll
        for (int ct = 0; ct < 3; ++ct)
            #pragma unroll
            for (int k = 0; k < 4; ++k)
                acc[ct] = __builtin_amdgcn_mfma_f32_16x16x32_bf16(w2_[k], afh[ct][k], acc[ct], 0, 0, 0);
        const floatx4 bb4 = *(const floatx4*)(b2s + nf + quad * 4);
        const floatx4 g4  = *(const floatx4*)(gs + nf + quad * 4);
        const floatx4 be4 = *(const floatx4*)(bs + nf + quad * 4);
        #pragma unroll
        for (int ct = 0; ct < 3; ++ct) {
            const int t = ct * 16 + l15;
            const float mn = mean_[t], rs = rstd_[t];
            floatx4 xv = *(const floatx4*)(xr + t * MSTR + nf + quad * 4);
            floatx4 nx;
            #pragma unroll
            for (int g = 0; g < 4; ++g) {
                const float ln1 = (xv[g] - mn) * rs * g4[g] + be4[g];
                nx[g] = acc[ct][g] + bb4[g] + ln1;
            }
            *(floatx4*)(xr + t * MSTR + nf + quad * 4) = nx;
        }
    }
    __syncthreads();
    ln_stats132(xr, mean_, rstd_, tid);
    __syncthreads();

    // ---- channels-first vectorized output ----
    for (int f = tid; f < 1536; f += 512) {
        const int c = f / 12, z4 = (f % 12) * 4;
        floatx4 o4;
        #pragma unroll
        for (int j = 0; j < 4; ++j)
            o4[j] = (xr[(z4 + j) * MSTR + c] - mean_[z4 + j]) * rstd_[z4 + j] * gs[c] + bs[c];
        *(floatx4*)(out + (long)(b * 128 + c) * 110592 + xx * 2304 + yy * 48 + z4) = o4;
    }
}

// -------------------------------------------------------------------------------------
extern "C" void kernel_launch(void* const* d_in, const int* in_sizes, int n_in,
                              void* d_out, int out_size, void* d_ws, size_t ws_size,
                              hipStream_t stream)
{
    const float* x    = (const float*)d_in[0];
    const float* px   = (const float*)d_in[1];
    const float* py   = (const float*)d_in[2];
    const float* pz   = (const float*)d_in[3];
    const float* wq[3]   = { (const float*)d_in[4],  (const float*)d_in[8],  (const float*)d_in[12] };
    const float* wkv[3]  = { (const float*)d_in[5],  (const float*)d_in[9],  (const float*)d_in[13] };
    const float* wout[3] = { (const float*)d_in[6],  (const float*)d_in[10], (const float*)d_in[14] };
    const float* bout[3] = { (const float*)d_in[7],  (const float*)d_in[11], (const float*)d_in[15] };
    const float* ln_g = (const float*)d_in[16];
    const float* ln_b = (const float*)d_in[17];
    const float* w1   = (const float*)d_in[18];
    const float* b1   = (const float*)d_in[19];
    const float* w2   = (const float*)d_in[20];
    const float* b2   = (const float*)d_in[21];

    // ws: A bf16 (56,623,104 B) | weights bf16 (458,752 B) | x2b bf16 (56,623,104 B)
    short* Ab  = (short*)d_ws;
    short* wb  = (short*)((char*)d_ws + 56623104);
    short* x2b = (short*)((char*)d_ws + 57081856);

    prep_weights<<<896, 256, 0, stream>>>(wq[0], wkv[0], wq[1], wkv[1], wq[2], wkv[2],
                                          wout[0], wout[1], wout[2], w1, w2, wb);
    prep_x2<<<4608, 256, 0, stream>>>(x, px, py, pz, x2b);

    attn_axis<0, 0><<<4608, 512, 0, stream>>>(x2b, wb,         wb + 147456, bout[0], Ab);
    attn_axis<1, 1><<<4608, 512, 0, stream>>>(x2b, wb + 49152, wb + 163840, bout[1], Ab);

    attn2_mlp<<<4608, 512, 0, stream>>>(x2b, Ab, wb + 98304, wb + 180224, bout[2],
                                        ln_g, ln_b, wb + 196608, b1, wb + 212992, b2,
                                        (float*)d_out);
}